// Round 5
// baseline (308.181 us; speedup 1.0000x reference)
//
#include <hip/hip_runtime.h>
#include <stdint.h>

#define D 256

typedef __attribute__((ext_vector_type(8))) short bf16x8;
typedef __attribute__((ext_vector_type(4))) float f32x4;

__device__ inline unsigned short f2bf(float f) {
    union { float f; uint32_t u; } v; v.f = f;
    return (unsigned short)((v.u + 0x7FFFu + ((v.u >> 16) & 1u)) >> 16);
}
__device__ inline float bf2f(unsigned short b) {
    return __uint_as_float(((uint32_t)b) << 16);
}

// segment geometry (padded to 1024-multiples for the block scan)
#define SEG0 0
#define SEG1 50176
#define SEG2 62464
#define CURTOT 66560          // 50176+12288+4096
#define NBLK 65               // seg0 blocks 0-48, seg1 49-60, seg2 61-64

#define WBLK 1536             // 6*65536/256
#define XBLK 25000            // 200000*256/8/256

// ---------- fused preprocessing: weights transpose + x->bf16 + edge count ----
struct PreArgs {
    const float* w[6];
    const float* x;
    unsigned short* wt;
    unsigned short* xb;
    const int* d0; const int* d1; const int* d2;
    int* cur;
    int E0, E01, Etot, cblk0;
};

__global__ __launch_bounds__(256) void fused_pre(PreArgs a)
{
    int b = blockIdx.x;
    if (b < WBLK) {
        // weights -> bf16 transposed [col][k]
        int t = b * 256 + threadIdx.x;
        int m = t >> 16, e = t & 65535;
        int col = e >> 8, k = e & 255;
        a.wt[t] = f2bf(a.w[m][(k << 8) + col]);
    } else if (b < WBLK + XBLK) {
        // x -> bf16, 8 elems/thread
        long t = (long)(b - WBLK) * 256 + threadIdx.x;
        const float4* p = (const float4*)a.x + t * 2;
        float4 v0 = p[0], v1 = p[1];
        unsigned short r[8] = {f2bf(v0.x), f2bf(v0.y), f2bf(v0.z), f2bf(v0.w),
                               f2bf(v1.x), f2bf(v1.y), f2bf(v1.z), f2bf(v1.w)};
        *(uint4*)(a.xb + t * 8) = *(uint4*)r;
    } else {
        // histogram of dst
        int e = (b - a.cblk0) * 256 + threadIdx.x;
        if (e >= a.Etot) return;
        int base, d;
        if (e < a.E0)       { base = SEG0; d = a.d0[e]; }
        else if (e < a.E01) { base = SEG1; d = a.d1[e - a.E0]; }
        else                { base = SEG2; d = a.d2[e - a.E01]; }
        atomicAdd(&a.cur[base + d], 1);
    }
}

// ---------- scan phase A: per-block (1024) exclusive scan; totals -> bsum ----
__global__ __launch_bounds__(256) void scan_blocks(
    int* __restrict__ cur, int* __restrict__ bsum)
{
    __shared__ int wsum[4];
    int tid = threadIdx.x, lane = tid & 63, wid = tid >> 6;
    int base = blockIdx.x * 1024 + tid * 4;
    int4 v = *(int4*)(cur + base);
    int t0 = v.x, t01 = t0 + v.y, t012 = t01 + v.z, tot = t012 + v.w;
    int incl = tot;
    #pragma unroll
    for (int ofs = 1; ofs < 64; ofs <<= 1) {
        int t = __shfl_up(incl, ofs, 64);
        if (lane >= ofs) incl += t;
    }
    if (lane == 63) wsum[wid] = incl;
    __syncthreads();
    if (tid == 0) {
        int run = 0;
        #pragma unroll
        for (int w = 0; w < 4; ++w) { int t = wsum[w]; wsum[w] = run; run += t; }
        bsum[blockIdx.x] = run;
    }
    __syncthreads();
    int texcl = wsum[wid] + incl - tot;
    v.x = texcl; v.y = texcl + t0; v.z = texcl + t01; v.w = texcl + t012;
    *(int4*)(cur + base) = v;
}

// ---------- scan phase B: segmented exclusive scan of 65 block sums ----------
__global__ __launch_bounds__(128) void scan_bsums(
    const int* __restrict__ bsum, int* __restrict__ bscan)
{
    __shared__ int s[NBLK];
    int tid = threadIdx.x;
    if (tid < NBLK) s[tid] = bsum[tid];
    __syncthreads();
    if (tid == 0) {
        int run = 0;
        for (int b = 0; b < 49; ++b)  { int t = s[b]; s[b] = run; run += t; }
        run = 0;
        for (int b = 49; b < 61; ++b) { int t = s[b]; s[b] = run; run += t; }
        run = 0;
        for (int b = 61; b < 65; ++b) { int t = s[b]; s[b] = run; run += t; }
    }
    __syncthreads();
    if (tid < NBLK) bscan[tid] = s[tid];
}

// ---------- scan phase C: add block offsets back ----------
__global__ __launch_bounds__(256) void scan_addback(
    int* __restrict__ cur, const int* __restrict__ bscan)
{
    int base = blockIdx.x * 1024 + threadIdx.x * 4;
    int add = bscan[blockIdx.x];
    int4 v = *(int4*)(cur + base);
    v.x += add; v.y += add; v.z += add; v.w += add;
    *(int4*)(cur + base) = v;
}

// fill: idx[cursor(dst)] = src; afterwards cur[] holds INCLUSIVE offsets
__global__ __launch_bounds__(256) void fill_all(
    const int* __restrict__ s0, const int* __restrict__ s1, const int* __restrict__ s2,
    const int* __restrict__ d0, const int* __restrict__ d1, const int* __restrict__ d2,
    int* __restrict__ cur, int* __restrict__ idx, int E0, int E01, int Etot)
{
    int e = blockIdx.x * 256 + threadIdx.x;
    if (e >= Etot) return;
    int base, d, s, ib;
    if (e < E0)       { base = SEG0; d = d0[e];       s = s0[e];       ib = 0; }
    else if (e < E01) { base = SEG1; d = d1[e - E0];  s = s1[e - E0];  ib = E0; }
    else              { base = SEG2; d = d2[e - E01]; s = s2[e - E01]; ib = E01; }
    int p = atomicAdd(&cur[base + d], 1);
    idx[ib + p] = s;
}

// ---------- gather + mean (one wave per dst row), bf16 in / bf16 out --------
__global__ __launch_bounds__(256) void gather_mean_k(
    const unsigned short* __restrict__ h, const int* __restrict__ idx,
    const int* __restrict__ curseg, unsigned short* __restrict__ mean, int M)
{
    int t = blockIdx.x * blockDim.x + threadIdx.x;
    int w = t >> 6, lane = t & 63;
    if (w >= M) return;
    int e0 = w ? curseg[w - 1] : 0;
    int e1 = curseg[w];
    float4 acc = make_float4(0.f, 0.f, 0.f, 0.f);
    int e = e0;
    for (; e + 1 < e1; e += 2) {
        int sa = idx[e], sb = idx[e + 1];
        ushort4 va = *(const ushort4*)(h + (size_t)sa * D + lane * 4);
        ushort4 vb = *(const ushort4*)(h + (size_t)sb * D + lane * 4);
        acc.x += bf2f(va.x) + bf2f(vb.x);
        acc.y += bf2f(va.y) + bf2f(vb.y);
        acc.z += bf2f(va.z) + bf2f(vb.z);
        acc.w += bf2f(va.w) + bf2f(vb.w);
    }
    if (e < e1) {
        int sa = idx[e];
        ushort4 va = *(const ushort4*)(h + (size_t)sa * D + lane * 4);
        acc.x += bf2f(va.x); acc.y += bf2f(va.y);
        acc.z += bf2f(va.z); acc.w += bf2f(va.w);
    }
    float r = 1.0f / fmaxf((float)(e1 - e0), 1.0f);
    ushort4 o;
    o.x = f2bf(acc.x * r); o.y = f2bf(acc.y * r);
    o.z = f2bf(acc.z * r); o.w = f2bf(acc.w * r);
    *(ushort4*)(mean + (size_t)w * D + lane * 4) = o;
}

// ---------- MFMA GEMM: out = relu(A1@W1 + A2@W2 + b) ----------
// 128x256 block tile (full N), 4 waves (2x2) of 64x128, K=512 (two 256 phases).
// A read ONCE per layer. W pre-transposed bf16 [col][k].
template<int FINAL>
__global__ __launch_bounds__(256, 2) void sage_gemm_mfma(
    const unsigned short* __restrict__ A1,
    const unsigned short* __restrict__ A2,
    const unsigned short* __restrict__ Wt1,
    const unsigned short* __restrict__ Wt2,
    const float* __restrict__ bias,
    void* __restrict__ outv,
    int M)
{
    __shared__ unsigned short As[128 * 32];   // 8 KB
    __shared__ unsigned short Bs[256 * 32];   // 16 KB

    int tid = threadIdx.x;
    int lane = tid & 63, wid = tid >> 6;
    int wr = wid >> 1, wc = wid & 1;
    int m0 = blockIdx.x * 128;
    int l15 = lane & 15, lq = lane >> 4;

    f32x4 acc[4][8] = {};

    for (int kt = 0; kt < 16; ++kt) {
        const unsigned short* A = (kt < 8) ? A1 : A2;
        const unsigned short* B = (kt < 8) ? Wt1 : Wt2;
        int kk = (kt & 7) * 32;
        // A tile 128x32 (8 KB): 512 chunks of 16B, 2/thread
        #pragma unroll
        for (int q = 0; q < 2; ++q) {
            int ch = q * 256 + tid;
            int r = ch >> 2, c16 = ch & 3;
            int gr = m0 + r; if (gr >= M) gr = M - 1;
            const unsigned short* src = A + (size_t)gr * 256 + kk + c16 * 8;
            __builtin_amdgcn_global_load_lds(
                (const __attribute__((address_space(1))) void*)src,
                (__attribute__((address_space(3))) void*)(As + (q * 256 + wid * 64) * 8),
                16, 0, 0);
        }
        // B tile 256x32 (16 KB): 1024 chunks of 16B, 4/thread
        #pragma unroll
        for (int q = 0; q < 4; ++q) {
            int ch = q * 256 + tid;
            int col = ch >> 2, c16 = ch & 3;
            const unsigned short* src = B + (size_t)col * 256 + kk + c16 * 8;
            __builtin_amdgcn_global_load_lds(
                (const __attribute__((address_space(1))) void*)src,
                (__attribute__((address_space(3))) void*)(Bs + (q * 256 + wid * 64) * 8),
                16, 0, 0);
        }
        __syncthreads();

        bf16x8 af[4], bfr[8];
        #pragma unroll
        for (int i = 0; i < 4; ++i)
            af[i] = *(const bf16x8*)(As + (wr * 64 + i * 16 + l15) * 32 + lq * 8);
        #pragma unroll
        for (int i = 0; i < 8; ++i)
            bfr[i] = *(const bf16x8*)(Bs + (wc * 128 + i * 16 + l15) * 32 + lq * 8);

        #pragma unroll
        for (int mr = 0; mr < 4; ++mr)
            #pragma unroll
            for (int nc = 0; nc < 8; ++nc)
                acc[mr][nc] = __builtin_amdgcn_mfma_f32_16x16x32_bf16(
                    af[mr], bfr[nc], acc[mr][nc], 0, 0, 0);
        __syncthreads();
    }

    // epilogue: bias + relu; C/D layout col=lane&15, row=(lane>>4)*4+reg
    #pragma unroll
    for (int nc = 0; nc < 8; ++nc) {
        int gc = wc * 128 + nc * 16 + l15;
        float bv = bias[gc];
        #pragma unroll
        for (int mr = 0; mr < 4; ++mr) {
            #pragma unroll
            for (int reg = 0; reg < 4; ++reg) {
                int gr = m0 + wr * 64 + mr * 16 + lq * 4 + reg;
                if (gr < M) {
                    float v = fmaxf(acc[mr][nc][reg] + bv, 0.f);
                    if (FINAL) ((float*)outv)[(size_t)gr * 256 + gc] = v;
                    else ((unsigned short*)outv)[(size_t)gr * 256 + gc] = f2bf(v);
                }
            }
        }
    }
}

extern "C" void kernel_launch(void* const* d_in, const int* in_sizes, int n_in,
                              void* d_out, int out_size, void* d_ws, size_t ws_size,
                              hipStream_t stream) {
    const float* x = (const float*)d_in[0];
    const float* Wself[3]  = {(const float*)d_in[1], (const float*)d_in[4], (const float*)d_in[7]};
    const float* Wneigh[3] = {(const float*)d_in[2], (const float*)d_in[5], (const float*)d_in[8]};
    const float* bias[3]   = {(const float*)d_in[3], (const float*)d_in[6], (const float*)d_in[9]};
    const int* src[3] = {(const int*)d_in[10], (const int*)d_in[12], (const int*)d_in[14]};
    const int* dst[3] = {(const int*)d_in[11], (const int*)d_in[13], (const int*)d_in[15]};
    int E[3]    = {in_sizes[10], in_sizes[12], in_sizes[14]};
    int ndst[3] = {50000, 12000, 4000};   // NODE_COUNTS[1..3] fixed by setup_inputs
    int E0 = E[0], E01 = E[0] + E[1], Etot = E[0] + E[1] + E[2];

    // workspace
    unsigned short* xb    = (unsigned short*)d_ws;           // 200000*256 bf16 (102.4 MB)
    unsigned short* h1b   = xb + (size_t)200000 * D;         // 50000*256
    unsigned short* h2b   = h1b + (size_t)50000 * D;         // 12000*256
    unsigned short* meanb = h2b + (size_t)12000 * D;         // 50000*256
    unsigned short* wt    = meanb + (size_t)50000 * D;       // 6*65536 [col][k]
    int* cur   = (int*)(wt + 6 * 65536);                     // CURTOT
    int* bsum  = cur + CURTOT;                               // 65 (pad 80)
    int* bscan = bsum + 80;                                  // 65 (pad 80)
    int* idxa  = bscan + 80;                                 // Etot (<=660000)

    hipMemsetAsync(cur, 0, CURTOT * sizeof(int), stream);

    PreArgs pa;
    pa.w[0] = Wself[0]; pa.w[1] = Wneigh[0];
    pa.w[2] = Wself[1]; pa.w[3] = Wneigh[1];
    pa.w[4] = Wself[2]; pa.w[5] = Wneigh[2];
    pa.x = x; pa.wt = wt; pa.xb = xb;
    pa.d0 = dst[0]; pa.d1 = dst[1]; pa.d2 = dst[2];
    pa.cur = cur; pa.E0 = E0; pa.E01 = E01; pa.Etot = Etot;
    pa.cblk0 = WBLK + XBLK;
    int cblk = (Etot + 255) / 256;
    fused_pre<<<WBLK + XBLK + cblk, 256, 0, stream>>>(pa);

    scan_blocks<<<NBLK, 256, 0, stream>>>(cur, bsum);
    scan_bsums<<<1, 128, 0, stream>>>(bsum, bscan);
    scan_addback<<<NBLK, 256, 0, stream>>>(cur, bscan);
    fill_all<<<(Etot + 255) / 256, 256, 0, stream>>>(src[0], src[1], src[2],
        dst[0], dst[1], dst[2], cur, idxa, E0, E01, Etot);

    const unsigned short* hin_b[3] = {xb, h1b, h2b};
    void* houts[3] = {h1b, h2b, d_out};
    int segb[3] = {SEG0, SEG1, SEG2};
    int idxb[3] = {0, E0, E01};

    for (int l = 0; l < 3; ++l) {
        int M = ndst[l];
        int gt = M * 64;
        gather_mean_k<<<(gt + 255) / 256, 256, 0, stream>>>(
            hin_b[l], idxa + idxb[l], cur + segb[l], meanb, M);

        dim3 grid((M + 127) / 128);
        if (l < 2)
            sage_gemm_mfma<0><<<grid, 256, 0, stream>>>(hin_b[l], meanb,
                wt + (size_t)(2 * l) * 65536, wt + (size_t)(2 * l + 1) * 65536,
                bias[l], houts[l], M);
        else
            sage_gemm_mfma<1><<<grid, 256, 0, stream>>>(hin_b[l], meanb,
                wt + (size_t)(2 * l) * 65536, wt + (size_t)(2 * l + 1) * 65536,
                bias[l], houts[l], M);
    }
}

// Round 6
// 290.175 us; speedup vs baseline: 1.0620x; 1.0620x over previous
//
#include <hip/hip_runtime.h>
#include <stdint.h>

#define D 256

typedef __attribute__((ext_vector_type(8))) short bf16x8;
typedef __attribute__((ext_vector_type(4))) float f32x4;

__device__ inline unsigned short f2bf(float f) {
    union { float f; uint32_t u; } v; v.f = f;
    return (unsigned short)((v.u + 0x7FFFu + ((v.u >> 16) & 1u)) >> 16);
}
__device__ inline float bf2f(unsigned short b) {
    return __uint_as_float(((uint32_t)b) << 16);
}

// segment geometry (padded to 1024-multiples for the block scan)
#define SEG0 0
#define SEG1 50176
#define SEG2 62464
#define CURTOT 66560          // 50176+12288+4096
#define NBLK 65               // seg0 blocks 0-48, seg1 49-60, seg2 61-64

#define WBLK 1536             // 6*65536/256
#define XBLK 6250             // 50000*256/8/256  (only rows the GEMM needs as A1)

// ---------- fused preprocessing: weights transpose + x[:50K]->bf16 + count ---
struct PreArgs {
    const float* w[6];
    const float* x;
    unsigned short* wt;
    unsigned short* xb;
    const int* d0; const int* d1; const int* d2;
    int* cur;
    int E0, E01, Etot, cblk0;
};

__global__ __launch_bounds__(256) void fused_pre(PreArgs a)
{
    int b = blockIdx.x;
    if (b < WBLK) {
        // weights -> bf16 transposed [col][k]
        int t = b * 256 + threadIdx.x;
        int m = t >> 16, e = t & 65535;
        int col = e >> 8, k = e & 255;
        a.wt[t] = f2bf(a.w[m][(k << 8) + col]);
    } else if (b < WBLK + XBLK) {
        // x rows [0,50000) -> bf16, 8 elems/thread
        long t = (long)(b - WBLK) * 256 + threadIdx.x;
        const float4* p = (const float4*)a.x + t * 2;
        float4 v0 = p[0], v1 = p[1];
        unsigned short r[8] = {f2bf(v0.x), f2bf(v0.y), f2bf(v0.z), f2bf(v0.w),
                               f2bf(v1.x), f2bf(v1.y), f2bf(v1.z), f2bf(v1.w)};
        *(uint4*)(a.xb + t * 8) = *(uint4*)r;
    } else {
        // histogram of dst
        int e = (b - a.cblk0) * 256 + threadIdx.x;
        if (e >= a.Etot) return;
        int base, d;
        if (e < a.E0)       { base = SEG0; d = a.d0[e]; }
        else if (e < a.E01) { base = SEG1; d = a.d1[e - a.E0]; }
        else                { base = SEG2; d = a.d2[e - a.E01]; }
        atomicAdd(&a.cur[base + d], 1);
    }
}

// ---------- scan phase A: per-block (1024) exclusive scan; totals -> bsum ----
__global__ __launch_bounds__(256) void scan_blocks(
    int* __restrict__ cur, int* __restrict__ bsum)
{
    __shared__ int wsum[4];
    int tid = threadIdx.x, lane = tid & 63, wid = tid >> 6;
    int base = blockIdx.x * 1024 + tid * 4;
    int4 v = *(int4*)(cur + base);
    int t0 = v.x, t01 = t0 + v.y, t012 = t01 + v.z, tot = t012 + v.w;
    int incl = tot;
    #pragma unroll
    for (int ofs = 1; ofs < 64; ofs <<= 1) {
        int t = __shfl_up(incl, ofs, 64);
        if (lane >= ofs) incl += t;
    }
    if (lane == 63) wsum[wid] = incl;
    __syncthreads();
    if (tid == 0) {
        int run = 0;
        #pragma unroll
        for (int w = 0; w < 4; ++w) { int t = wsum[w]; wsum[w] = run; run += t; }
        bsum[blockIdx.x] = run;
    }
    __syncthreads();
    int texcl = wsum[wid] + incl - tot;
    v.x = texcl; v.y = texcl + t0; v.z = texcl + t01; v.w = texcl + t012;
    *(int4*)(cur + base) = v;
}

// ---------- scan phase B: segmented exclusive scan of 65 block sums ----------
__global__ __launch_bounds__(128) void scan_bsums(
    const int* __restrict__ bsum, int* __restrict__ bscan)
{
    __shared__ int s[NBLK];
    int tid = threadIdx.x;
    if (tid < NBLK) s[tid] = bsum[tid];
    __syncthreads();
    if (tid == 0) {
        int run = 0;
        for (int b = 0; b < 49; ++b)  { int t = s[b]; s[b] = run; run += t; }
        run = 0;
        for (int b = 49; b < 61; ++b) { int t = s[b]; s[b] = run; run += t; }
        run = 0;
        for (int b = 61; b < 65; ++b) { int t = s[b]; s[b] = run; run += t; }
    }
    __syncthreads();
    if (tid < NBLK) bscan[tid] = s[tid];
}

// ---------- scan phase C: add block offsets back ----------
__global__ __launch_bounds__(256) void scan_addback(
    int* __restrict__ cur, const int* __restrict__ bscan)
{
    int base = blockIdx.x * 1024 + threadIdx.x * 4;
    int add = bscan[blockIdx.x];
    int4 v = *(int4*)(cur + base);
    v.x += add; v.y += add; v.z += add; v.w += add;
    *(int4*)(cur + base) = v;
}

// fill: idx[cursor(dst)] = src; afterwards cur[] holds INCLUSIVE offsets
__global__ __launch_bounds__(256) void fill_all(
    const int* __restrict__ s0, const int* __restrict__ s1, const int* __restrict__ s2,
    const int* __restrict__ d0, const int* __restrict__ d1, const int* __restrict__ d2,
    int* __restrict__ cur, int* __restrict__ idx, int E0, int E01, int Etot)
{
    int e = blockIdx.x * 256 + threadIdx.x;
    if (e >= Etot) return;
    int base, d, s, ib;
    if (e < E0)       { base = SEG0; d = d0[e];       s = s0[e];       ib = 0; }
    else if (e < E01) { base = SEG1; d = d1[e - E0];  s = s1[e - E0];  ib = E0; }
    else              { base = SEG2; d = d2[e - E01]; s = s2[e - E01]; ib = E01; }
    int p = atomicAdd(&cur[base + d], 1);
    idx[ib + p] = s;
}

// ---------- gather + mean (one wave per dst row), 4-deep unroll --------------
// cur holds inclusive offsets: e0 = w ? curseg[w-1] : 0, e1 = curseg[w]
template<int BF16IN>
__global__ __launch_bounds__(256) void gather_mean_k(
    const void* __restrict__ hv, const int* __restrict__ idx,
    const int* __restrict__ curseg, unsigned short* __restrict__ mean, int M)
{
    int t = blockIdx.x * blockDim.x + threadIdx.x;
    int w = t >> 6, lane = t & 63;
    if (w >= M) return;
    int e0 = w ? curseg[w - 1] : 0;
    int e1 = curseg[w];
    float4 acc0 = make_float4(0.f, 0.f, 0.f, 0.f);
    float4 acc1 = make_float4(0.f, 0.f, 0.f, 0.f);
    int e = e0;
    if (BF16IN) {
        const unsigned short* h = (const unsigned short*)hv;
        for (; e + 3 < e1; e += 4) {
            int sa = idx[e], sb = idx[e + 1], sc = idx[e + 2], sd = idx[e + 3];
            ushort4 va = *(const ushort4*)(h + (size_t)sa * D + lane * 4);
            ushort4 vb = *(const ushort4*)(h + (size_t)sb * D + lane * 4);
            ushort4 vc = *(const ushort4*)(h + (size_t)sc * D + lane * 4);
            ushort4 vd = *(const ushort4*)(h + (size_t)sd * D + lane * 4);
            acc0.x += bf2f(va.x) + bf2f(vb.x);
            acc0.y += bf2f(va.y) + bf2f(vb.y);
            acc0.z += bf2f(va.z) + bf2f(vb.z);
            acc0.w += bf2f(va.w) + bf2f(vb.w);
            acc1.x += bf2f(vc.x) + bf2f(vd.x);
            acc1.y += bf2f(vc.y) + bf2f(vd.y);
            acc1.z += bf2f(vc.z) + bf2f(vd.z);
            acc1.w += bf2f(vc.w) + bf2f(vd.w);
        }
        for (; e < e1; ++e) {
            int sa = idx[e];
            ushort4 va = *(const ushort4*)(h + (size_t)sa * D + lane * 4);
            acc0.x += bf2f(va.x); acc0.y += bf2f(va.y);
            acc0.z += bf2f(va.z); acc0.w += bf2f(va.w);
        }
    } else {
        const float* h = (const float*)hv;
        for (; e + 3 < e1; e += 4) {
            int sa = idx[e], sb = idx[e + 1], sc = idx[e + 2], sd = idx[e + 3];
            float4 va = *((const float4*)(h + (size_t)sa * D) + lane);
            float4 vb = *((const float4*)(h + (size_t)sb * D) + lane);
            float4 vc = *((const float4*)(h + (size_t)sc * D) + lane);
            float4 vd = *((const float4*)(h + (size_t)sd * D) + lane);
            acc0.x += va.x + vb.x; acc0.y += va.y + vb.y;
            acc0.z += va.z + vb.z; acc0.w += va.w + vb.w;
            acc1.x += vc.x + vd.x; acc1.y += vc.y + vd.y;
            acc1.z += vc.z + vd.z; acc1.w += vc.w + vd.w;
        }
        for (; e < e1; ++e) {
            int sa = idx[e];
            float4 va = *((const float4*)(h + (size_t)sa * D) + lane);
            acc0.x += va.x; acc0.y += va.y; acc0.z += va.z; acc0.w += va.w;
        }
    }
    acc0.x += acc1.x; acc0.y += acc1.y; acc0.z += acc1.z; acc0.w += acc1.w;
    float r = 1.0f / fmaxf((float)(e1 - e0), 1.0f);
    ushort4 o;
    o.x = f2bf(acc0.x * r); o.y = f2bf(acc0.y * r);
    o.z = f2bf(acc0.z * r); o.w = f2bf(acc0.w * r);
    *(ushort4*)(mean + (size_t)w * D + lane * 4) = o;
}

// ---------- MFMA GEMM: out = relu(A1@W1 + A2@W2 + b) ----------
// 128x256 block tile (full N), 4 waves (2x2) of 64x128, K=512 (two 256 phases).
// A read ONCE per layer. W pre-transposed bf16 [col][k].
template<int FINAL>
__global__ __launch_bounds__(256, 2) void sage_gemm_mfma(
    const unsigned short* __restrict__ A1,
    const unsigned short* __restrict__ A2,
    const unsigned short* __restrict__ Wt1,
    const unsigned short* __restrict__ Wt2,
    const float* __restrict__ bias,
    void* __restrict__ outv,
    int M)
{
    __shared__ unsigned short As[128 * 32];   // 8 KB
    __shared__ unsigned short Bs[256 * 32];   // 16 KB

    int tid = threadIdx.x;
    int lane = tid & 63, wid = tid >> 6;
    int wr = wid >> 1, wc = wid & 1;
    int m0 = blockIdx.x * 128;
    int l15 = lane & 15, lq = lane >> 4;

    f32x4 acc[4][8] = {};

    for (int kt = 0; kt < 16; ++kt) {
        const unsigned short* A = (kt < 8) ? A1 : A2;
        const unsigned short* B = (kt < 8) ? Wt1 : Wt2;
        int kk = (kt & 7) * 32;
        #pragma unroll
        for (int q = 0; q < 2; ++q) {
            int ch = q * 256 + tid;
            int r = ch >> 2, c16 = ch & 3;
            int gr = m0 + r; if (gr >= M) gr = M - 1;
            const unsigned short* src = A + (size_t)gr * 256 + kk + c16 * 8;
            __builtin_amdgcn_global_load_lds(
                (const __attribute__((address_space(1))) void*)src,
                (__attribute__((address_space(3))) void*)(As + (q * 256 + wid * 64) * 8),
                16, 0, 0);
        }
        #pragma unroll
        for (int q = 0; q < 4; ++q) {
            int ch = q * 256 + tid;
            int col = ch >> 2, c16 = ch & 3;
            const unsigned short* src = B + (size_t)col * 256 + kk + c16 * 8;
            __builtin_amdgcn_global_load_lds(
                (const __attribute__((address_space(1))) void*)src,
                (__attribute__((address_space(3))) void*)(Bs + (q * 256 + wid * 64) * 8),
                16, 0, 0);
        }
        __syncthreads();

        bf16x8 af[4], bfr[8];
        #pragma unroll
        for (int i = 0; i < 4; ++i)
            af[i] = *(const bf16x8*)(As + (wr * 64 + i * 16 + l15) * 32 + lq * 8);
        #pragma unroll
        for (int i = 0; i < 8; ++i)
            bfr[i] = *(const bf16x8*)(Bs + (wc * 128 + i * 16 + l15) * 32 + lq * 8);

        #pragma unroll
        for (int mr = 0; mr < 4; ++mr)
            #pragma unroll
            for (int nc = 0; nc < 8; ++nc)
                acc[mr][nc] = __builtin_amdgcn_mfma_f32_16x16x32_bf16(
                    af[mr], bfr[nc], acc[mr][nc], 0, 0, 0);
        __syncthreads();
    }

    // epilogue: bias + relu; C/D layout col=lane&15, row=(lane>>4)*4+reg
    #pragma unroll
    for (int nc = 0; nc < 8; ++nc) {
        int gc = wc * 128 + nc * 16 + l15;
        float bv = bias[gc];
        #pragma unroll
        for (int mr = 0; mr < 4; ++mr) {
            #pragma unroll
            for (int reg = 0; reg < 4; ++reg) {
                int gr = m0 + wr * 64 + mr * 16 + lq * 4 + reg;
                if (gr < M) {
                    float v = fmaxf(acc[mr][nc][reg] + bv, 0.f);
                    if (FINAL) ((float*)outv)[(size_t)gr * 256 + gc] = v;
                    else ((unsigned short*)outv)[(size_t)gr * 256 + gc] = f2bf(v);
                }
            }
        }
    }
}

extern "C" void kernel_launch(void* const* d_in, const int* in_sizes, int n_in,
                              void* d_out, int out_size, void* d_ws, size_t ws_size,
                              hipStream_t stream) {
    const float* x = (const float*)d_in[0];
    const float* Wself[3]  = {(const float*)d_in[1], (const float*)d_in[4], (const float*)d_in[7]};
    const float* Wneigh[3] = {(const float*)d_in[2], (const float*)d_in[5], (const float*)d_in[8]};
    const float* bias[3]   = {(const float*)d_in[3], (const float*)d_in[6], (const float*)d_in[9]};
    const int* src[3] = {(const int*)d_in[10], (const int*)d_in[12], (const int*)d_in[14]};
    const int* dst[3] = {(const int*)d_in[11], (const int*)d_in[13], (const int*)d_in[15]};
    int E[3]    = {in_sizes[10], in_sizes[12], in_sizes[14]};
    int ndst[3] = {50000, 12000, 4000};   // NODE_COUNTS[1..3] fixed by setup_inputs
    int E0 = E[0], E01 = E[0] + E[1], Etot = E[0] + E[1] + E[2];

    // workspace
    unsigned short* xb    = (unsigned short*)d_ws;           // 50000*256 bf16 (GEMM A1)
    unsigned short* h1b   = xb + (size_t)50000 * D;          // 50000*256
    unsigned short* h2b   = h1b + (size_t)50000 * D;         // 12000*256
    unsigned short* meanb = h2b + (size_t)12000 * D;         // 50000*256
    unsigned short* wt    = meanb + (size_t)50000 * D;       // 6*65536 [col][k]
    int* cur   = (int*)(wt + 6 * 65536);                     // CURTOT
    int* bsum  = cur + CURTOT;                               // 65 (pad 80)
    int* bscan = bsum + 80;                                  // 65 (pad 80)
    int* idxa  = bscan + 80;                                 // Etot (<=660000)

    hipMemsetAsync(cur, 0, CURTOT * sizeof(int), stream);

    PreArgs pa;
    pa.w[0] = Wself[0]; pa.w[1] = Wneigh[0];
    pa.w[2] = Wself[1]; pa.w[3] = Wneigh[1];
    pa.w[4] = Wself[2]; pa.w[5] = Wneigh[2];
    pa.x = x; pa.wt = wt; pa.xb = xb;
    pa.d0 = dst[0]; pa.d1 = dst[1]; pa.d2 = dst[2];
    pa.cur = cur; pa.E0 = E0; pa.E01 = E01; pa.Etot = Etot;
    pa.cblk0 = WBLK + XBLK;
    int cblk = (Etot + 255) / 256;
    fused_pre<<<WBLK + XBLK + cblk, 256, 0, stream>>>(pa);

    scan_blocks<<<NBLK, 256, 0, stream>>>(cur, bsum);
    scan_bsums<<<1, 128, 0, stream>>>(bsum, bscan);
    scan_addback<<<NBLK, 256, 0, stream>>>(cur, bscan);
    fill_all<<<(Etot + 255) / 256, 256, 0, stream>>>(src[0], src[1], src[2],
        dst[0], dst[1], dst[2], cur, idxa, E0, E01, Etot);

    const unsigned short* hin_b[3] = {xb, h1b, h2b};
    void* houts[3] = {h1b, h2b, d_out};
    int segb[3] = {SEG0, SEG1, SEG2};
    int idxb[3] = {0, E0, E01};

    for (int l = 0; l < 3; ++l) {
        int M = ndst[l];
        int gt = M * 64;
        if (l == 0)
            gather_mean_k<0><<<(gt + 255) / 256, 256, 0, stream>>>(
                x, idxa + idxb[l], cur + segb[l], meanb, M);
        else
            gather_mean_k<1><<<(gt + 255) / 256, 256, 0, stream>>>(
                hin_b[l], idxa + idxb[l], cur + segb[l], meanb, M);

        dim3 grid((M + 127) / 128);
        if (l < 2)
            sage_gemm_mfma<0><<<grid, 256, 0, stream>>>(hin_b[l], meanb,
                wt + (size_t)(2 * l) * 65536, wt + (size_t)(2 * l + 1) * 65536,
                bias[l], houts[l], M);
        else
            sage_gemm_mfma<1><<<grid, 256, 0, stream>>>(hin_b[l], meanb,
                wt + (size_t)(2 * l) * 65536, wt + (size_t)(2 * l + 1) * 65536,
                bias[l], houts[l], M);
    }
}

// Round 7
// 270.931 us; speedup vs baseline: 1.1375x; 1.0710x over previous
//
#include <hip/hip_runtime.h>
#include <stdint.h>

#define D 256

typedef __attribute__((ext_vector_type(8))) short bf16x8;
typedef __attribute__((ext_vector_type(4))) float f32x4;

__device__ inline unsigned short f2bf(float f) {
    union { float f; uint32_t u; } v; v.f = f;
    return (unsigned short)((v.u + 0x7FFFu + ((v.u >> 16) & 1u)) >> 16);
}
__device__ inline float bf2f(unsigned short b) {
    return __uint_as_float(((uint32_t)b) << 16);
}

// segment geometry (padded to 1024-multiples for the block scan)
#define SEG0 0
#define SEG1 50176
#define SEG2 62464
#define CURTOT 66560          // 50176+12288+4096
#define NBLK 65               // seg0 blocks 0-48, seg1 49-60, seg2 61-64

#define WBLK 1536             // 6*65536/256

// ---------- fused preprocessing: weights transpose + edge count --------------
struct PreArgs {
    const float* w[6];
    unsigned short* wt;
    const int* d0; const int* d1; const int* d2;
    int* cur;
    int E0, E01, Etot;
};

__global__ __launch_bounds__(256) void fused_pre(PreArgs a)
{
    int b = blockIdx.x;
    if (b < WBLK) {
        // weights -> bf16 transposed [col][k]
        int t = b * 256 + threadIdx.x;
        int m = t >> 16, e = t & 65535;
        int col = e >> 8, k = e & 255;
        a.wt[t] = f2bf(a.w[m][(k << 8) + col]);
    } else {
        // histogram of dst
        int e = (b - WBLK) * 256 + threadIdx.x;
        if (e >= a.Etot) return;
        int base, d;
        if (e < a.E0)       { base = SEG0; d = a.d0[e]; }
        else if (e < a.E01) { base = SEG1; d = a.d1[e - a.E0]; }
        else                { base = SEG2; d = a.d2[e - a.E01]; }
        atomicAdd(&a.cur[base + d], 1);
    }
}

// ---------- scan phase A: per-block (1024) exclusive scan; totals -> bsum ----
__global__ __launch_bounds__(256) void scan_blocks(
    int* __restrict__ cur, int* __restrict__ bsum)
{
    __shared__ int wsum[4];
    int tid = threadIdx.x, lane = tid & 63, wid = tid >> 6;
    int base = blockIdx.x * 1024 + tid * 4;
    int4 v = *(int4*)(cur + base);
    int t0 = v.x, t01 = t0 + v.y, t012 = t01 + v.z, tot = t012 + v.w;
    int incl = tot;
    #pragma unroll
    for (int ofs = 1; ofs < 64; ofs <<= 1) {
        int t = __shfl_up(incl, ofs, 64);
        if (lane >= ofs) incl += t;
    }
    if (lane == 63) wsum[wid] = incl;
    __syncthreads();
    if (tid == 0) {
        int run = 0;
        #pragma unroll
        for (int w = 0; w < 4; ++w) { int t = wsum[w]; wsum[w] = run; run += t; }
        bsum[blockIdx.x] = run;
    }
    __syncthreads();
    int texcl = wsum[wid] + incl - tot;
    v.x = texcl; v.y = texcl + t0; v.z = texcl + t01; v.w = texcl + t012;
    *(int4*)(cur + base) = v;
}

// ---------- scan phase B: segmented exclusive scan of 65 block sums ----------
__global__ __launch_bounds__(128) void scan_bsums(
    const int* __restrict__ bsum, int* __restrict__ bscan)
{
    __shared__ int s[NBLK];
    int tid = threadIdx.x;
    if (tid < NBLK) s[tid] = bsum[tid];
    __syncthreads();
    if (tid == 0) {
        int run = 0;
        for (int b = 0; b < 49; ++b)  { int t = s[b]; s[b] = run; run += t; }
        run = 0;
        for (int b = 49; b < 61; ++b) { int t = s[b]; s[b] = run; run += t; }
        run = 0;
        for (int b = 61; b < 65; ++b) { int t = s[b]; s[b] = run; run += t; }
    }
    __syncthreads();
    if (tid < NBLK) bscan[tid] = s[tid];
}

// ---------- scan phase C: add block offsets back ----------
__global__ __launch_bounds__(256) void scan_addback(
    int* __restrict__ cur, const int* __restrict__ bscan)
{
    int base = blockIdx.x * 1024 + threadIdx.x * 4;
    int add = bscan[blockIdx.x];
    int4 v = *(int4*)(cur + base);
    v.x += add; v.y += add; v.z += add; v.w += add;
    *(int4*)(cur + base) = v;
}

// fill: idx[cursor(dst)] = src; afterwards cur[] holds INCLUSIVE offsets
__global__ __launch_bounds__(256) void fill_all(
    const int* __restrict__ s0, const int* __restrict__ s1, const int* __restrict__ s2,
    const int* __restrict__ d0, const int* __restrict__ d1, const int* __restrict__ d2,
    int* __restrict__ cur, int* __restrict__ idx, int E0, int E01, int Etot)
{
    int e = blockIdx.x * 256 + threadIdx.x;
    if (e >= Etot) return;
    int base, d, s, ib;
    if (e < E0)       { base = SEG0; d = d0[e];       s = s0[e];       ib = 0; }
    else if (e < E01) { base = SEG1; d = d1[e - E0];  s = s1[e - E0];  ib = E0; }
    else              { base = SEG2; d = d2[e - E01]; s = s2[e - E01]; ib = E01; }
    int p = atomicAdd(&cur[base + d], 1);
    idx[ib + p] = s;
}

// ---------- gather + mean (one wave per dst row), 4-deep unroll --------------
template<int BF16IN>
__global__ __launch_bounds__(256) void gather_mean_k(
    const void* __restrict__ hv, const int* __restrict__ idx,
    const int* __restrict__ curseg, unsigned short* __restrict__ mean, int M)
{
    int t = blockIdx.x * blockDim.x + threadIdx.x;
    int w = t >> 6, lane = t & 63;
    if (w >= M) return;
    int e0 = w ? curseg[w - 1] : 0;
    int e1 = curseg[w];
    float4 acc0 = make_float4(0.f, 0.f, 0.f, 0.f);
    float4 acc1 = make_float4(0.f, 0.f, 0.f, 0.f);
    int e = e0;
    if (BF16IN) {
        const unsigned short* h = (const unsigned short*)hv;
        for (; e + 3 < e1; e += 4) {
            int sa = idx[e], sb = idx[e + 1], sc = idx[e + 2], sd = idx[e + 3];
            ushort4 va = *(const ushort4*)(h + (size_t)sa * D + lane * 4);
            ushort4 vb = *(const ushort4*)(h + (size_t)sb * D + lane * 4);
            ushort4 vc = *(const ushort4*)(h + (size_t)sc * D + lane * 4);
            ushort4 vd = *(const ushort4*)(h + (size_t)sd * D + lane * 4);
            acc0.x += bf2f(va.x) + bf2f(vb.x);
            acc0.y += bf2f(va.y) + bf2f(vb.y);
            acc0.z += bf2f(va.z) + bf2f(vb.z);
            acc0.w += bf2f(va.w) + bf2f(vb.w);
            acc1.x += bf2f(vc.x) + bf2f(vd.x);
            acc1.y += bf2f(vc.y) + bf2f(vd.y);
            acc1.z += bf2f(vc.z) + bf2f(vd.z);
            acc1.w += bf2f(vc.w) + bf2f(vd.w);
        }
        for (; e < e1; ++e) {
            int sa = idx[e];
            ushort4 va = *(const ushort4*)(h + (size_t)sa * D + lane * 4);
            acc0.x += bf2f(va.x); acc0.y += bf2f(va.y);
            acc0.z += bf2f(va.z); acc0.w += bf2f(va.w);
        }
    } else {
        const float* h = (const float*)hv;
        for (; e + 3 < e1; e += 4) {
            int sa = idx[e], sb = idx[e + 1], sc = idx[e + 2], sd = idx[e + 3];
            float4 va = *((const float4*)(h + (size_t)sa * D) + lane);
            float4 vb = *((const float4*)(h + (size_t)sb * D) + lane);
            float4 vc = *((const float4*)(h + (size_t)sc * D) + lane);
            float4 vd = *((const float4*)(h + (size_t)sd * D) + lane);
            acc0.x += va.x + vb.x; acc0.y += va.y + vb.y;
            acc0.z += va.z + vb.z; acc0.w += va.w + vb.w;
            acc1.x += vc.x + vd.x; acc1.y += vc.y + vd.y;
            acc1.z += vc.z + vd.z; acc1.w += vc.w + vd.w;
        }
        for (; e < e1; ++e) {
            int sa = idx[e];
            float4 va = *((const float4*)(h + (size_t)sa * D) + lane);
            acc0.x += va.x; acc0.y += va.y; acc0.z += va.z; acc0.w += va.w;
        }
    }
    acc0.x += acc1.x; acc0.y += acc1.y; acc0.z += acc1.z; acc0.w += acc1.w;
    float r = 1.0f / fmaxf((float)(e1 - e0), 1.0f);
    ushort4 o;
    o.x = f2bf(acc0.x * r); o.y = f2bf(acc0.y * r);
    o.z = f2bf(acc0.z * r); o.w = f2bf(acc0.w * r);
    *(ushort4*)(mean + (size_t)w * D + lane * 4) = o;
}

// ---------- MFMA GEMM: out = relu(A1@W1 + A2@W2 + b) ----------
// 128x128 block tile, 4 waves (2x2) of 64x64, K=512 (two 256 phases).
// A1F32: phase-0 A staged from fp32 global via reg + f2bf + ds_write
// (identical As layout); else global_load_lds from bf16.
template<int FINAL, int A1F32>
__global__ __launch_bounds__(256) void sage_gemm_mfma(
    const void* __restrict__ A1v,
    const unsigned short* __restrict__ A2,
    const unsigned short* __restrict__ Wt1,
    const unsigned short* __restrict__ Wt2,
    const float* __restrict__ bias,
    void* __restrict__ outv,
    int M)
{
    __shared__ unsigned short As[128 * 32];   // 8 KB
    __shared__ unsigned short Bs[128 * 32];   // 8 KB

    int tid = threadIdx.x;
    int lane = tid & 63, wid = tid >> 6;
    int wr = wid >> 1, wc = wid & 1;
    int m0 = blockIdx.x * 128, n0 = blockIdx.y * 128;
    int l15 = lane & 15, lq = lane >> 4;

    f32x4 acc[4][4] = {};

    for (int kt = 0; kt < 16; ++kt) {
        int kk = (kt & 7) * 32;
        // ---- A tile 128x32 bf16 (8 KB) ----
        if (A1F32 && kt < 8) {
            const float* A = (const float*)A1v;
            #pragma unroll
            for (int q = 0; q < 2; ++q) {
                int ch = q * 256 + tid;          // 0..511 chunks of 16B
                int r = ch >> 2, c16 = ch & 3;
                int gr = m0 + r; if (gr >= M) gr = M - 1;
                const float* s = A + (size_t)gr * 256 + kk + c16 * 8;
                float4 u0 = *(const float4*)s;
                float4 u1 = *(const float4*)(s + 4);
                unsigned short rr[8] = {f2bf(u0.x), f2bf(u0.y), f2bf(u0.z), f2bf(u0.w),
                                        f2bf(u1.x), f2bf(u1.y), f2bf(u1.z), f2bf(u1.w)};
                *(uint4*)(As + ch * 8) = *(uint4*)rr;
            }
        } else {
            const unsigned short* A = (kt < 8) ? (const unsigned short*)A1v : A2;
            #pragma unroll
            for (int q = 0; q < 2; ++q) {
                int ch = q * 256 + tid;
                int r = ch >> 2, c16 = ch & 3;
                int gr = m0 + r; if (gr >= M) gr = M - 1;
                const unsigned short* s = A + (size_t)gr * 256 + kk + c16 * 8;
                __builtin_amdgcn_global_load_lds(
                    (const __attribute__((address_space(1))) void*)s,
                    (__attribute__((address_space(3))) void*)(As + (q * 256 + wid * 64) * 8),
                    16, 0, 0);
            }
        }
        // ---- B tile 128x32 bf16 (8 KB) ----
        {
            const unsigned short* B = (kt < 8) ? Wt1 : Wt2;
            #pragma unroll
            for (int q = 0; q < 2; ++q) {
                int ch = q * 256 + tid;
                int col = ch >> 2, c16 = ch & 3;
                const unsigned short* s = B + (size_t)(n0 + col) * 256 + kk + c16 * 8;
                __builtin_amdgcn_global_load_lds(
                    (const __attribute__((address_space(1))) void*)s,
                    (__attribute__((address_space(3))) void*)(Bs + (q * 256 + wid * 64) * 8),
                    16, 0, 0);
            }
        }
        __syncthreads();

        bf16x8 af[4], bfr[4];
        #pragma unroll
        for (int i = 0; i < 4; ++i) {
            af[i]  = *(const bf16x8*)(As + (wr * 64 + i * 16 + l15) * 32 + lq * 8);
            bfr[i] = *(const bf16x8*)(Bs + (wc * 64 + i * 16 + l15) * 32 + lq * 8);
        }
        #pragma unroll
        for (int mr = 0; mr < 4; ++mr)
            #pragma unroll
            for (int nc = 0; nc < 4; ++nc)
                acc[mr][nc] = __builtin_amdgcn_mfma_f32_16x16x32_bf16(
                    af[mr], bfr[nc], acc[mr][nc], 0, 0, 0);
        __syncthreads();
    }

    // epilogue: bias + relu; C/D layout col=lane&15, row=(lane>>4)*4+reg
    #pragma unroll
    for (int nc = 0; nc < 4; ++nc) {
        int gc = n0 + wc * 64 + nc * 16 + l15;
        float bv = bias[gc];
        #pragma unroll
        for (int mr = 0; mr < 4; ++mr) {
            #pragma unroll
            for (int reg = 0; reg < 4; ++reg) {
                int gr = m0 + wr * 64 + mr * 16 + lq * 4 + reg;
                if (gr < M) {
                    float v = fmaxf(acc[mr][nc][reg] + bv, 0.f);
                    if (FINAL) ((float*)outv)[(size_t)gr * 256 + gc] = v;
                    else ((unsigned short*)outv)[(size_t)gr * 256 + gc] = f2bf(v);
                }
            }
        }
    }
}

extern "C" void kernel_launch(void* const* d_in, const int* in_sizes, int n_in,
                              void* d_out, int out_size, void* d_ws, size_t ws_size,
                              hipStream_t stream) {
    const float* x = (const float*)d_in[0];
    const float* Wself[3]  = {(const float*)d_in[1], (const float*)d_in[4], (const float*)d_in[7]};
    const float* Wneigh[3] = {(const float*)d_in[2], (const float*)d_in[5], (const float*)d_in[8]};
    const float* bias[3]   = {(const float*)d_in[3], (const float*)d_in[6], (const float*)d_in[9]};
    const int* src[3] = {(const int*)d_in[10], (const int*)d_in[12], (const int*)d_in[14]};
    const int* dst[3] = {(const int*)d_in[11], (const int*)d_in[13], (const int*)d_in[15]};
    int E[3]    = {in_sizes[10], in_sizes[12], in_sizes[14]};
    int ndst[3] = {50000, 12000, 4000};   // NODE_COUNTS[1..3] fixed by setup_inputs
    int E0 = E[0], E01 = E[0] + E[1], Etot = E[0] + E[1] + E[2];

    // workspace
    unsigned short* h1b   = (unsigned short*)d_ws;           // 50000*256
    unsigned short* h2b   = h1b + (size_t)50000 * D;         // 12000*256
    unsigned short* meanb = h2b + (size_t)12000 * D;         // 50000*256
    unsigned short* wt    = meanb + (size_t)50000 * D;       // 6*65536 [col][k]
    int* cur   = (int*)(wt + 6 * 65536);                     // CURTOT
    int* bsum  = cur + CURTOT;                               // 65 (pad 80)
    int* bscan = bsum + 80;                                  // 65 (pad 80)
    int* idxa  = bscan + 80;                                 // Etot (<=660000)

    hipMemsetAsync(cur, 0, CURTOT * sizeof(int), stream);

    PreArgs pa;
    pa.w[0] = Wself[0]; pa.w[1] = Wneigh[0];
    pa.w[2] = Wself[1]; pa.w[3] = Wneigh[1];
    pa.w[4] = Wself[2]; pa.w[5] = Wneigh[2];
    pa.wt = wt;
    pa.d0 = dst[0]; pa.d1 = dst[1]; pa.d2 = dst[2];
    pa.cur = cur; pa.E0 = E0; pa.E01 = E01; pa.Etot = Etot;
    int cblk = (Etot + 255) / 256;
    fused_pre<<<WBLK + cblk, 256, 0, stream>>>(pa);

    scan_blocks<<<NBLK, 256, 0, stream>>>(cur, bsum);
    scan_bsums<<<1, 128, 0, stream>>>(bsum, bscan);
    scan_addback<<<NBLK, 256, 0, stream>>>(cur, bscan);
    fill_all<<<(Etot + 255) / 256, 256, 0, stream>>>(src[0], src[1], src[2],
        dst[0], dst[1], dst[2], cur, idxa, E0, E01, Etot);

    int segb[3] = {SEG0, SEG1, SEG2};
    int idxb[3] = {0, E0, E01};

    for (int l = 0; l < 3; ++l) {
        int M = ndst[l];
        int gt = M * 64;
        if (l == 0)
            gather_mean_k<0><<<(gt + 255) / 256, 256, 0, stream>>>(
                x, idxa + idxb[l], cur + segb[l], meanb, M);
        else
            gather_mean_k<1><<<(gt + 255) / 256, 256, 0, stream>>>(
                l == 1 ? h1b : h2b, idxa + idxb[l], cur + segb[l], meanb, M);

        dim3 grid((M + 127) / 128, 2);
        if (l == 0)
            sage_gemm_mfma<0, 1><<<grid, 256, 0, stream>>>(x, meanb,
                wt + 0 * 65536, wt + 1 * 65536, bias[0], h1b, M);
        else if (l == 1)
            sage_gemm_mfma<0, 0><<<grid, 256, 0, stream>>>(h1b, meanb,
                wt + 2 * 65536, wt + 3 * 65536, bias[1], h2b, M);
        else
            sage_gemm_mfma<1, 0><<<grid, 256, 0, stream>>>(h2b, meanb,
                wt + 4 * 65536, wt + 5 * 65536, bias[2], d_out, M);
    }
}